// Round 10
// baseline (209.808 us; speedup 1.0000x reference)
//
#include <hip/hip_runtime.h>
#include <hip/hip_bf16.h>

typedef __attribute__((ext_vector_type(4))) float f32x4;
typedef __attribute__((ext_vector_type(8))) short s16x8;

constexpr int NN   = 8192;
constexpr int KIN  = 512;
constexpr int KOUT = 128;

constexpr int JCHUNK = 8;
constexpr int JLEN   = NN / JCHUNK;   // 1024
constexpr int SG     = 32;            // stage width (cols)
constexpr int NS     = JLEN / SG;     // 32 stages
constexpr int HBUF   = 8192;          // bytes per hT stage buffer (128 rows x 32 cols bf16)

__device__ __forceinline__ ushort f2bf(float x) {
    union { float f; unsigned u; } v; v.f = x;
    unsigned r = (v.u + 0x7fffu + ((v.u >> 16) & 1u)) >> 16;
    return (ushort)r;
}

__device__ __forceinline__ void gload_lds16(const void* g, void* l) {
    __builtin_amdgcn_global_load_lds((const __attribute__((address_space(1))) void*)g,
                                     (__attribute__((address_space(3))) void*)l, 16, 0, 0);
}

// ---------------- Kernel A: h = input @ W ; hT(bf16), s, t ----------------
__global__ __launch_bounds__(256) void kA(const float* __restrict__ inp,
                                          const float* __restrict__ W,
                                          const float* __restrict__ a_s,
                                          const float* __restrict__ a_n,
                                          ushort* __restrict__ hT,
                                          float* __restrict__ s_out,
                                          float* __restrict__ t_out) {
    __shared__ float smem[16 * 512];
    const int t = threadIdx.x;
    const int rbase = blockIdx.x * 16;

#pragma unroll
    for (int it = 0; it < 8; ++it) {
        int idx = it * 256 + t;
        int r = idx >> 7;
        int c4 = (idx & 127) << 2;
        *(f32x4*)(&smem[r * 512 + c4]) =
            *(const f32x4*)(inp + (size_t)(rbase + r) * KIN + c4);
    }
    __syncthreads();

    const int c0 = (t & 31) * 4;
    const int rg = (t >> 5) * 2;
    float acc[2][4] = {};
#pragma unroll 4
    for (int k = 0; k < KIN; ++k) {
        f32x4 w4 = *(const f32x4*)(W + (size_t)k * KOUT + c0);
        float a0 = smem[(rg + 0) * 512 + k];
        float a1 = smem[(rg + 1) * 512 + k];
#pragma unroll
        for (int cc = 0; cc < 4; ++cc) {
            acc[0][cc] += a0 * w4[cc];
            acc[1][cc] += a1 * w4[cc];
        }
    }
    __syncthreads();

    float* h_lds = smem;                        // [16][128]
#pragma unroll
    for (int rr = 0; rr < 2; ++rr) {
        f32x4 v = {acc[rr][0], acc[rr][1], acc[rr][2], acc[rr][3]};
        *(f32x4*)(&h_lds[(rg + rr) * 128 + c0]) = v;
    }
    __syncthreads();

    {
        const int col = t >> 1;
        const int r0 = (t & 1) * 8;
        ushort tmp[8];
#pragma unroll
        for (int rr = 0; rr < 8; ++rr) tmp[rr] = f2bf(h_lds[(r0 + rr) * 128 + col]);
        *(f32x4*)(hT + (size_t)col * NN + rbase + r0) = *(f32x4*)&tmp[0];
    }

    {
        const int w = t >> 6, lane = t & 63;
        float as1 = a_s[lane], as2 = a_s[64 + lane];
        float an1 = a_n[lane], an2 = a_n[64 + lane];
#pragma unroll
        for (int rr = 0; rr < 4; ++rr) {
            int row = w * 4 + rr;
            float h1 = h_lds[row * 128 + lane];
            float h2 = h_lds[row * 128 + 64 + lane];
            float ps = h1 * as1 + h2 * as2;
            float pt = h1 * an1 + h2 * an2;
#pragma unroll
            for (int off = 32; off; off >>= 1) {
                ps += __shfl_xor(ps, off);
                pt += __shfl_xor(pt, off);
            }
            if (lane == 0) {
                s_out[rbase + row] = ps;
                t_out[rbase + row] = pt;
            }
        }
    }
}

// ---------------- Kernel B v9: R9 structure at 2x occupancy ----------------
// grid 1024: rb = bid>>3 (64 rows), jc = bid&7 (1024 cols). 4 blocks/CU (16 waves/CU).
// Pipeline identical to R9: ping-pong regs (M/adj/t) + hT DMA ring-3, vmcnt(8)/stage,
// per-block column-phase rotation retained (mild win, harmless).
__global__ __launch_bounds__(256, 4) void kB(const float* __restrict__ Mmat,
                                             const float* __restrict__ adjm,
                                             const ushort* __restrict__ hT,
                                             const float* __restrict__ s_in,
                                             const float* __restrict__ t_in,
                                             float* __restrict__ o_part,
                                             float* __restrict__ l_part) {
    __shared__ f32x4 LDSQ[3 * HBUF / 16];
    char* LDS = (char*)LDSQ;

    const int tid = threadIdx.x;
    const int w = tid >> 6;
    const int l = tid & 63;
    const int lrow = l & 15;             // MFMA A-row this lane owns
    const int kgrp = l >> 4;             // MFMA k-group (8 cols each)
    const int rb = blockIdx.x >> 3;
    const int jc = blockIdx.x & 7;
    const int j0 = jc * JLEN;
    const int i = rb * 64 + w * 16 + lrow;

    const int PH = (int)((blockIdx.x * 23u) & (unsigned)(NS - 1));
#define SP(SS) ((((SS) + PH) & (NS - 1)))

    const float si = s_in[i];

    // per-lane fragment-layout sources
    const float* Mp = Mmat + (size_t)i * NN + j0 + kgrp * 8;
    const float* Ap = adjm + (size_t)i * NN + j0 + kgrp * 8;
    const float* tp = t_in + j0 + kgrp * 8;

    // hT DMA source (pre-swizzled global, linear LDS dst) — validated path
    const int rl8 = l >> 3;
    const int rl4 = l >> 2, c4i = l & 3;
    const int csH = c4i ^ (rl8 & 3);
    const ushort* gH0 = hT + (size_t)(w * 32 + rl4) * NN + j0 + csH * 8;
    const ushort* gH1 = gH0 + (size_t)16 * NN;
    const int hdst0 = (w * 32) * 64;
    const int hdst1 = (w * 32 + 16) * 64;
    const int Ch = lrow * 64 + ((kgrp ^ ((lrow >> 1) & 3)) << 4);

    f32x4 acc[8];
#pragma unroll
    for (int ct = 0; ct < 8; ++ct) acc[ct] = (f32x4){0.f, 0.f, 0.f, 0.f};
    float lsum = 0.f;

#define DMA_H(HB, SS)                                                        \
    gload_lds16(gH0 + (size_t)SP(SS) * SG, LDS + (HB) + hdst0);              \
    gload_lds16(gH1 + (size_t)SP(SS) * SG, LDS + (HB) + hdst1);

#define LD_R(M0, M1, A0, A1, T0, T1, SS)                           \
    M0 = *(const f32x4*)(Mp + SP(SS) * SG);                        \
    M1 = *(const f32x4*)(Mp + SP(SS) * SG + 4);                    \
    A0 = *(const f32x4*)(Ap + SP(SS) * SG);                        \
    A1 = *(const f32x4*)(Ap + SP(SS) * SG + 4);                    \
    T0 = *(const f32x4*)(tp + SP(SS) * SG);                        \
    T1 = *(const f32x4*)(tp + SP(SS) * SG + 4);

#define COMPUTE(HB, M0, M1, A0, A1, T0, T1)                                      \
    {                                                                            \
        s16x8 af;                                                                \
        _Pragma("unroll")                                                        \
        for (int e = 0; e < 4; ++e) {                                            \
            float x = (si + (T0)[e]) * (M0)[e];                                  \
            x = fmaxf(x, 0.2f * x);                                              \
            float p = __expf(x) * (A0)[e];          /* adj is exactly 0 or 1 */  \
            lsum += p;                                                           \
            af[e] = (short)f2bf(p);                                              \
        }                                                                        \
        _Pragma("unroll")                                                        \
        for (int e = 0; e < 4; ++e) {                                            \
            float x = (si + (T1)[e]) * (M1)[e];                                  \
            x = fmaxf(x, 0.2f * x);                                              \
            float p = __expf(x) * (A1)[e];                                       \
            lsum += p;                                                           \
            af[4 + e] = (short)f2bf(p);                                          \
        }                                                                        \
        const char* hb = LDS + (HB) + Ch;                                        \
        _Pragma("unroll")                                                        \
        for (int ct = 0; ct < 8; ++ct) {                                         \
            s16x8 bf = *(const s16x8*)(hb + ct * 1024);                          \
            acc[ct] = __builtin_amdgcn_mfma_f32_16x16x32_bf16(af, bf, acc[ct], 0, 0, 0); \
        }                                                                        \
    }

    // ping-pong register sets
    f32x4 mA0, mA1, aA0, aA1, tA0, tA1;
    f32x4 mB0, mB1, aB0, aB1, tB0, tB1;
    int hA = 0, hB = HBUF, hC = 2 * HBUF;

    // prologue: group(0) then group(1) -> 16 outstanding
    DMA_H(hA, 0)
    LD_R(mA0, mA1, aA0, aA1, tA0, tA1, 0)
    DMA_H(hB, 1)
    LD_R(mB0, mB1, aB0, aB1, tB0, tB1, 1)

#pragma unroll 1
    for (int s = 0; s < NS; s += 2) {
        const int s2 = (s + 2 < NS) ? s + 2 : NS - 1;   // clamped (harmless dup at tail)
        const int s3 = (s + 3 < NS) ? s + 3 : NS - 1;

        // ---- even sub-iter: stage s (set A, buf hA) ----
        asm volatile("s_waitcnt vmcnt(8)" ::: "memory");  // group(s) landed
        __builtin_amdgcn_s_barrier();
        asm volatile("" ::: "memory");
        DMA_H(hC, s2)
        COMPUTE(hA, mA0, mA1, aA0, aA1, tA0, tA1)
        LD_R(mA0, mA1, aA0, aA1, tA0, tA1, s2)

        // ---- odd sub-iter: stage s+1 (set B, buf hB) ----
        asm volatile("s_waitcnt vmcnt(8)" ::: "memory");  // group(s+1) landed
        __builtin_amdgcn_s_barrier();
        asm volatile("" ::: "memory");
        DMA_H(hA, s3)
        COMPUTE(hB, mB0, mB1, aB0, aB1, tB0, tB1)
        LD_R(mB0, mB1, aB0, aB1, tB0, tB1, s3)

        // rotate ring: (hA,hB,hC) <- (hC,hA,hB)
        int ht = hA; hA = hC; hC = hB; hB = ht;
    }
#undef DMA_H
#undef LD_R
#undef COMPUTE
#undef SP

    // denominator partials: lanes {l, l^16, l^32, l^48} share row lrow
    lsum += __shfl_xor(lsum, 16);
    lsum += __shfl_xor(lsum, 32);
    if (l < 16) l_part[(size_t)jc * NN + i] = lsum;

    // o partials (D layout: row=(lane>>4)*4+reg, col=lane&15)
    float* op = o_part + (size_t)jc * NN * KOUT;
#pragma unroll
    for (int ct = 0; ct < 8; ++ct) {
#pragma unroll
        for (int r = 0; r < 4; ++r) {
            int gi = rb * 64 + w * 16 + kgrp * 4 + r;
            int col = ct * 16 + lrow;
            op[(size_t)gi * KOUT + col] = acc[ct][r];
        }
    }
}

// ---------------- Kernel C: reduce partials, divide, ELU ----------------
__global__ __launch_bounds__(256) void kC(const float* __restrict__ o_part,
                                          const float* __restrict__ l_part,
                                          float* __restrict__ out) {
    const int idx = blockIdx.x * 256 + threadIdx.x;
    const int i = idx >> 7;
    float osum = 0.f, lsum = 0.f;
#pragma unroll
    for (int p = 0; p < JCHUNK; ++p) {
        osum += o_part[(size_t)p * NN * KOUT + idx];
        lsum += l_part[(size_t)p * NN + i];
    }
    float v = osum / lsum;
    out[idx] = v > 0.f ? v : (__expf(v) - 1.f);
}

extern "C" void kernel_launch(void* const* d_in, const int* in_sizes, int n_in,
                              void* d_out, int out_size, void* d_ws, size_t ws_size,
                              hipStream_t stream) {
    const float* inp = (const float*)d_in[0];
    const float* adj = (const float*)d_in[1];
    const float* Mm  = (const float*)d_in[2];
    const float* W   = (const float*)d_in[3];
    const float* a_s = (const float*)d_in[4];
    const float* a_n = (const float*)d_in[5];
    float* out = (float*)d_out;

    char* ws = (char*)d_ws;
    ushort* hT    = (ushort*)(ws + 0);              //  2 MB   [128][8192] bf16
    float*  s_buf = (float*)(ws + 2097152);         //  32 KB
    float*  t_buf = (float*)(ws + 2129920);         //  32 KB
    float*  l_prt = (float*)(ws + 2162688);         //  256 KB [8][8192]
    float*  o_prt = (float*)(ws + 4194304);         //  32 MB  [8][8192][128]

    hipLaunchKernelGGL(kA, dim3(512), dim3(256), 0, stream, inp, W, a_s, a_n, hT, s_buf, t_buf);
    hipLaunchKernelGGL(kB, dim3(128 * JCHUNK), dim3(256), 0, stream, Mm, adj, hT, s_buf, t_buf, o_prt, l_prt);
    hipLaunchKernelGGL(kC, dim3(4096), dim3(256), 0, stream, o_prt, l_prt, out);
}